// Round 4
// baseline (204.633 us; speedup 1.0000x reference)
//
#include <hip/hip_runtime.h>

// LATTE forward, algebraically reduced (verified R2/R3):
//   h_m = v * (in_deg_m>0); gate g[n,h] = cnt[n]*softmax_h(lrelu(v.rl + v.rr))[h];
//   o = v*g; LayerNorm; ReLU.  v = feat@Wr + br.
// R4: coalesced output via per-wave LDS transpose (fixes 2.3x write amplification);
//     flags scatter uses test-before-write (partial-line byte stores punch through L2).

#define NN 50000
#define KDIM 256
#define EE 800000
#define NEG 0.2f
#define EPSV 1e-5f
#define NTILES 3125   // 50000/16
#define EB4 200000    // EE/4 edge-quads
#define FLB 782       // ceil(EB4/256)

typedef __attribute__((ext_vector_type(8))) short bf16x8;
typedef __attribute__((ext_vector_type(4))) float f32x4;

#define LDS_FENCE() asm volatile("s_waitcnt lgkmcnt(0)" ::: "memory")

__device__ __forceinline__ short f2bf(float f) {   // RNE fp32->bf16
    unsigned u = __float_as_uint(f);
    u += 0x7fff + ((u >> 16) & 1);
    return (short)(u >> 16);
}

__device__ __forceinline__ void ld_g2l_16(void* lds, const void* g) {
    __builtin_amdgcn_global_load_lds(
        (const __attribute__((address_space(1))) unsigned int*)g,
        (__attribute__((address_space(3))) unsigned int*)lds, 16, 0, 0);
}

// blocks [0,FLB): degree flags (test-before-write, int4 edge loads).
// blocks [FLB,FLB+256): Wt[n][k] = bf16(Wr[k][n]).
__global__ __launch_bounds__(256) void prep_kernel(
    const int* __restrict__ d0, const int* __restrict__ d1,
    const int* __restrict__ d2, unsigned char* __restrict__ fl,
    const float* __restrict__ Wr, unsigned short* __restrict__ Wt)
{
    int b = blockIdx.x, t = threadIdx.x;
    if (b < FLB) {
        int i = b * 256 + t;
        if (i < EB4) {
            int4 e0 = reinterpret_cast<const int4*>(d0)[i];
            int4 e1 = reinterpret_cast<const int4*>(d1)[i];
            int4 e2 = reinterpret_cast<const int4*>(d2)[i];
            // reads are cacheable; stores shrink to ~#distinct nodes. 0->1 races benign.
            if (!fl[e0.x]) fl[e0.x] = 1;
            if (!fl[e0.y]) fl[e0.y] = 1;
            if (!fl[e0.z]) fl[e0.z] = 1;
            if (!fl[e0.w]) fl[e0.w] = 1;
            if (!fl[NN + e1.x]) fl[NN + e1.x] = 1;
            if (!fl[NN + e1.y]) fl[NN + e1.y] = 1;
            if (!fl[NN + e1.z]) fl[NN + e1.z] = 1;
            if (!fl[NN + e1.w]) fl[NN + e1.w] = 1;
            if (!fl[2 * NN + e2.x]) fl[2 * NN + e2.x] = 1;
            if (!fl[2 * NN + e2.y]) fl[2 * NN + e2.y] = 1;
            if (!fl[2 * NN + e2.z]) fl[2 * NN + e2.z] = 1;
            if (!fl[2 * NN + e2.w]) fl[2 * NN + e2.w] = 1;
        }
    } else {
        int n = b - FLB;
        Wt[n * 256 + t] = (unsigned short)f2bf(Wr[t * 256 + n]);
    }
}

// 512 threads = 8 waves. wave's tile = blockIdx.x + 512*wave; tile = 16 rows x 256 cols.
// mfma 16x16x32 bf16: A[m=lane&15][k=quad*8+j], B[k][n=lane&15], C row=quad*4+reg col=lane&15.
__global__ __launch_bounds__(512, 4) void fused_kernel(
    const float* __restrict__ feat, const unsigned short* __restrict__ Wt,
    const float* __restrict__ br, const float* __restrict__ rl,
    const float* __restrict__ rr, const float* __restrict__ gamma,
    const float* __restrict__ beta, const unsigned char* __restrict__ fl,
    float* __restrict__ out)
{
    // phase 1: one K-half of B^T, XOR-swizzled (slot s: n=s>>4, ks=(s&15)^(n&15))
    // phase 2 (after compute): per-wave 8KB float scratch for the store transpose
    __shared__ __align__(16) char smem[65536];
    unsigned short* Bs = (unsigned short*)smem;
    const int t = threadIdx.x;
    const int wave = t >> 6, lane = t & 63;
    const int cl = lane & 15, quad = lane >> 4;
    const int tile = blockIdx.x + 512 * wave;
    const bool act = tile < NTILES;
    const int row0 = tile * 16;

    f32x4 acc[16];
#pragma unroll
    for (int i = 0; i < 16; ++i) acc[i] = (f32x4){0.f, 0.f, 0.f, 0.f};

    const float* arow = feat + (size_t)(act ? (row0 + cl) : 0) * KDIM;

#pragma unroll
    for (int half = 0; half < 2; ++half) {
        if (half) __syncthreads();         // protect LDS before overwrite
#pragma unroll
        for (int c = 0; c < 8; ++c) {      // stage 64KB B-half: 8 slots/thread
            int s = c * 512 + t;
            int n = s >> 4;
            int ks = (s & 15) ^ (n & 15);
            const unsigned short* g = Wt + n * 256 + half * 128 + ks * 8;
            ld_g2l_16(&Bs[(size_t)(c * 512 + wave * 64) * 8], g);
        }
        __syncthreads();                   // drains vmcnt for the DMA
        if (act) {
#pragma unroll
            for (int kk = 0; kk < 4; ++kk) {
                int k0 = half * 128 + kk * 32 + quad * 8;
                float4 a0 = *reinterpret_cast<const float4*>(arow + k0);
                float4 a1 = *reinterpret_cast<const float4*>(arow + k0 + 4);
                bf16x8 af;
                af[0] = f2bf(a0.x); af[1] = f2bf(a0.y);
                af[2] = f2bf(a0.z); af[3] = f2bf(a0.w);
                af[4] = f2bf(a1.x); af[5] = f2bf(a1.y);
                af[6] = f2bf(a1.z); af[7] = f2bf(a1.w);
                int ks = kk * 4 + quad;
#pragma unroll
                for (int ct = 0; ct < 16; ++ct) {
                    int n = ct * 16 + cl;
                    bf16x8 bf = *reinterpret_cast<const bf16x8*>(
                        &Bs[(size_t)(n * 16 + (ks ^ (n & 15))) * 8]);
                    acc[ct] = __builtin_amdgcn_mfma_f32_16x16x32_bf16(af, bf, acc[ct], 0, 0, 0);
                }
            }
        }
    }
    __syncthreads();   // ALL waves done reading Bs; LDS becomes per-wave scratch
    if (!act) return;

    // ---- fused epilogue (per wave: 16 rows x 256 cols, C-layout) ----
#pragma unroll
    for (int ct = 0; ct < 16; ++ct) {
        float bc = br[ct * 16 + cl];
#pragma unroll
        for (int r = 0; r < 4; ++r) acc[ct][r] += bc;
    }
    // per-head dots -> logits z[h][r]
    float z[4][4];
#pragma unroll
    for (int h = 0; h < 4; ++h) {
        float sl[4] = {0, 0, 0, 0}, sr[4] = {0, 0, 0, 0};
#pragma unroll
        for (int j = 0; j < 4; ++j) {
            int ct = h * 4 + j;
            float rlc = rl[ct * 16 + cl], rrc = rr[ct * 16 + cl];
#pragma unroll
            for (int r = 0; r < 4; ++r) {
                sl[r] += acc[ct][r] * rlc;
                sr[r] += acc[ct][r] * rrc;
            }
        }
#pragma unroll
        for (int off = 1; off < 16; off <<= 1)
#pragma unroll
            for (int r = 0; r < 4; ++r) {
                sl[r] += __shfl_xor(sl[r], off, 64);
                sr[r] += __shfl_xor(sr[r], off, 64);
            }
#pragma unroll
        for (int r = 0; r < 4; ++r) {
            float x = sl[r] + sr[r];
            z[h][r] = x > 0.f ? x : NEG * x;
        }
    }
    // softmax over heads + count gate (vectorized flag read: 4 rows per quad)
    uchar4 fq0 = *reinterpret_cast<const uchar4*>(fl + row0 + quad * 4);
    uchar4 fq1 = *reinterpret_cast<const uchar4*>(fl + NN + row0 + quad * 4);
    uchar4 fq2 = *reinterpret_cast<const uchar4*>(fl + 2 * NN + row0 + quad * 4);
    float c0[4] = {(float)fq0.x, (float)fq0.y, (float)fq0.z, (float)fq0.w};
    float c1[4] = {(float)fq1.x, (float)fq1.y, (float)fq1.z, (float)fq1.w};
    float c2[4] = {(float)fq2.x, (float)fq2.y, (float)fq2.z, (float)fq2.w};
    float gg[4][4];   // [h][r]
#pragma unroll
    for (int r = 0; r < 4; ++r) {
        float mx = fmaxf(fmaxf(z[0][r], z[1][r]), fmaxf(z[2][r], z[3][r]));
        float e0 = __expf(z[0][r] - mx), e1 = __expf(z[1][r] - mx);
        float e2 = __expf(z[2][r] - mx), e3 = __expf(z[3][r] - mx);
        float cnt = 1.f + c0[r] + c1[r] + c2[r];
        float inv = cnt / (e0 + e1 + e2 + e3);
        gg[0][r] = e0 * inv; gg[1][r] = e1 * inv;
        gg[2][r] = e2 * inv; gg[3][r] = e3 * inv;
    }
    // gate + LN stats
    float s[4] = {0, 0, 0, 0}, s2[4] = {0, 0, 0, 0};
#pragma unroll
    for (int ct = 0; ct < 16; ++ct) {
        int h = ct >> 2;
#pragma unroll
        for (int r = 0; r < 4; ++r) {
            float o = acc[ct][r] * gg[h][r];
            acc[ct][r] = o;
            s[r] += o;
            s2[r] += o * o;
        }
    }
#pragma unroll
    for (int off = 1; off < 16; off <<= 1)
#pragma unroll
        for (int r = 0; r < 4; ++r) {
            s[r] += __shfl_xor(s[r], off, 64);
            s2[r] += __shfl_xor(s2[r], off, 64);
        }
    float mu[4], rstd[4];
#pragma unroll
    for (int r = 0; r < 4; ++r) {
        mu[r] = s[r] * (1.f / 256.f);
        float var = s2[r] * (1.f / 256.f) - mu[r] * mu[r];
        rstd[r] = rsqrtf(var + EPSV);
    }
    // LN + ReLU into regs
#pragma unroll
    for (int ct = 0; ct < 16; ++ct) {
        float ga = gamma[ct * 16 + cl], be = beta[ct * 16 + cl];
#pragma unroll
        for (int r = 0; r < 4; ++r)
            acc[ct][r] = fmaxf((acc[ct][r] - mu[r]) * rstd[r] * ga + be, 0.f);
    }
    // coalesced store: per-wave 8KB LDS transpose, 2 passes x 8 rows
    float* tb = reinterpret_cast<float*>(smem) + wave * 2048;
#pragma unroll
    for (int p = 0; p < 2; ++p) {
#pragma unroll
        for (int ct = 0; ct < 16; ++ct) {
            tb[(quad * 2 + 0) * 256 + ct * 16 + cl] = acc[ct][2 * p + 0];
            tb[(quad * 2 + 1) * 256 + ct * 16 + cl] = acc[ct][2 * p + 1];
        }
        LDS_FENCE();   // same-wave cross-lane RAW on LDS
#pragma unroll
        for (int sl8 = 0; sl8 < 8; ++sl8) {
            int trow = (sl8 >> 1) * 4 + 2 * p + (sl8 & 1);
            float4 v4 = *reinterpret_cast<const float4*>(&tb[sl8 * 256 + lane * 4]);
            *reinterpret_cast<float4*>(&out[(size_t)(row0 + trow) * 256 + lane * 4]) = v4;
        }
        LDS_FENCE();   // WAR: reads complete before next pass overwrites
    }
}

extern "C" void kernel_launch(void* const* d_in, const int* in_sizes, int n_in,
                              void* d_out, int out_size, void* d_ws, size_t ws_size,
                              hipStream_t stream) {
    const float* feat = (const float*)d_in[0];
    const float* Wr   = (const float*)d_in[3];
    const float* br   = (const float*)d_in[4];
    const float* rl   = (const float*)d_in[7];
    const float* rr   = (const float*)d_in[8];
    const float* gam  = (const float*)d_in[9];
    const float* bet  = (const float*)d_in[10];
    const int* dst0   = (const int*)d_in[12];
    const int* dst1   = (const int*)d_in[14];
    const int* dst2   = (const int*)d_in[16];
    float* out = (float*)d_out;
    unsigned char* fl  = (unsigned char*)d_ws;                    // 150000 B
    unsigned short* Wt = (unsigned short*)((char*)d_ws + 262144); // 128 KB, 16B-aligned

    hipMemsetAsync(fl, 0, 3 * NN, stream);
    prep_kernel<<<FLB + 256, 256, 0, stream>>>(dst0, dst1, dst2, fl, Wr, Wt);
    fused_kernel<<<512, 512, 0, stream>>>(feat, Wt, br, rl, rr, gam, bet, fl, out);
}

// Round 5
// 183.804 us; speedup vs baseline: 1.1133x; 1.1133x over previous
//
#include <hip/hip_runtime.h>

// LATTE forward, algebraically reduced (verified R2/R3):
//   h_m = v * (in_deg_m>0); gate g[n,h] = cnt[n]*softmax_h(lrelu(v.rl + v.rr))[h];
//   o = v*g; LayerNorm; ReLU.  v = feat@Wr + br.
// R5: __launch_bounds__(512,2) — R3/R4 used (512,4) => 128-reg budget with a 64-AGPR
//     acc => epilogue spilled to scratch (HBM): that was the 2.3-2.9x FETCH/WRITE excess.
//     LN folded into the store-transpose passes to shrink the live set.

#define NN 50000
#define KDIM 256
#define EE 800000
#define NEG 0.2f
#define EPSV 1e-5f
#define NTILES 3125   // 50000/16
#define EB4 200000    // EE/4 edge-quads
#define FLB 782       // ceil(EB4/256)

typedef __attribute__((ext_vector_type(8))) short bf16x8;
typedef __attribute__((ext_vector_type(4))) float f32x4;

#define LDS_FENCE() asm volatile("s_waitcnt lgkmcnt(0)" ::: "memory")

__device__ __forceinline__ short f2bf(float f) {   // RNE fp32->bf16
    unsigned u = __float_as_uint(f);
    u += 0x7fff + ((u >> 16) & 1);
    return (short)(u >> 16);
}

__device__ __forceinline__ void ld_g2l_16(void* lds, const void* g) {
    __builtin_amdgcn_global_load_lds(
        (const __attribute__((address_space(1))) unsigned int*)g,
        (__attribute__((address_space(3))) unsigned int*)lds, 16, 0, 0);
}

// blocks [0,FLB): degree flags (test-before-write, int4 edge loads).
// blocks [FLB,FLB+8): Wt[n][k] = bf16(Wr[k][n]) via LDS (coalesced reads, 64B/thread writes).
__global__ __launch_bounds__(256) void prep_kernel(
    const int* __restrict__ d0, const int* __restrict__ d1,
    const int* __restrict__ d2, unsigned char* __restrict__ fl,
    const float* __restrict__ Wr, unsigned short* __restrict__ Wt)
{
    __shared__ float ws[32 * 256];   // 32 KB
    int b = blockIdx.x, t = threadIdx.x;
    if (b < FLB) {
        int i = b * 256 + t;
        if (i < EB4) {
            int4 e0 = reinterpret_cast<const int4*>(d0)[i];
            int4 e1 = reinterpret_cast<const int4*>(d1)[i];
            int4 e2 = reinterpret_cast<const int4*>(d2)[i];
            if (!fl[e0.x]) fl[e0.x] = 1;
            if (!fl[e0.y]) fl[e0.y] = 1;
            if (!fl[e0.z]) fl[e0.z] = 1;
            if (!fl[e0.w]) fl[e0.w] = 1;
            if (!fl[NN + e1.x]) fl[NN + e1.x] = 1;
            if (!fl[NN + e1.y]) fl[NN + e1.y] = 1;
            if (!fl[NN + e1.z]) fl[NN + e1.z] = 1;
            if (!fl[NN + e1.w]) fl[NN + e1.w] = 1;
            if (!fl[2 * NN + e2.x]) fl[2 * NN + e2.x] = 1;
            if (!fl[2 * NN + e2.y]) fl[2 * NN + e2.y] = 1;
            if (!fl[2 * NN + e2.z]) fl[2 * NN + e2.z] = 1;
            if (!fl[2 * NN + e2.w]) fl[2 * NN + e2.w] = 1;
        }
    } else {
        int kb = (b - FLB) * 32;
#pragma unroll
        for (int i = 0; i < 32; ++i)           // coalesced row loads
            ws[i * 256 + t] = Wr[(size_t)(kb + i) * 256 + t];
        __syncthreads();
#pragma unroll
        for (int c = 0; c < 4; ++c) {          // thread t = output row n
            bf16x8 o;
#pragma unroll
            for (int j = 0; j < 8; ++j)
                o[j] = f2bf(ws[(c * 8 + j) * 256 + t]);
            *reinterpret_cast<bf16x8*>(&Wt[(size_t)t * 256 + kb + c * 8]) = o;
        }
    }
}

// 512 threads = 8 waves. wave's tile = blockIdx.x + 512*wave; tile = 16 rows x 256 cols.
// mfma 16x16x32 bf16: A[m=lane&15][k=quad*8+j], B[k][n=lane&15], C row=quad*4+reg col=lane&15.
__global__ __launch_bounds__(512, 2) void fused_kernel(
    const float* __restrict__ feat, const unsigned short* __restrict__ Wt,
    const float* __restrict__ br, const float* __restrict__ rl,
    const float* __restrict__ rr, const float* __restrict__ gamma,
    const float* __restrict__ beta, const unsigned char* __restrict__ fl,
    float* __restrict__ out)
{
    // phase 1: one K-half of B^T, XOR-swizzled (slot s: n=s>>4, ks=(s&15)^(n&15))
    // phase 2 (after compute): per-wave 8KB float scratch for the store transpose
    __shared__ __align__(16) char smem[65536];
    unsigned short* Bs = (unsigned short*)smem;
    const int t = threadIdx.x;
    const int wave = t >> 6, lane = t & 63;
    const int cl = lane & 15, quad = lane >> 4;
    const int tile = blockIdx.x + 512 * wave;
    const bool act = tile < NTILES;
    const int row0 = tile * 16;

    f32x4 acc[16];
#pragma unroll
    for (int i = 0; i < 16; ++i) acc[i] = (f32x4){0.f, 0.f, 0.f, 0.f};

    const float* arow = feat + (size_t)(act ? (row0 + cl) : 0) * KDIM;

#pragma unroll
    for (int half = 0; half < 2; ++half) {
        if (half) __syncthreads();         // protect LDS before overwrite
#pragma unroll
        for (int c = 0; c < 8; ++c) {      // stage 64KB B-half: 8 slots/thread
            int s = c * 512 + t;
            int n = s >> 4;
            int ks = (s & 15) ^ (n & 15);
            const unsigned short* g = Wt + n * 256 + half * 128 + ks * 8;
            ld_g2l_16(&Bs[(size_t)(c * 512 + wave * 64) * 8], g);
        }
        __syncthreads();                   // drains vmcnt for the DMA
        if (act) {
#pragma unroll
            for (int kk = 0; kk < 4; ++kk) {
                int k0 = half * 128 + kk * 32 + quad * 8;
                float4 a0 = *reinterpret_cast<const float4*>(arow + k0);
                float4 a1 = *reinterpret_cast<const float4*>(arow + k0 + 4);
                bf16x8 af;
                af[0] = f2bf(a0.x); af[1] = f2bf(a0.y);
                af[2] = f2bf(a0.z); af[3] = f2bf(a0.w);
                af[4] = f2bf(a1.x); af[5] = f2bf(a1.y);
                af[6] = f2bf(a1.z); af[7] = f2bf(a1.w);
                int ks = kk * 4 + quad;
#pragma unroll
                for (int ct = 0; ct < 16; ++ct) {
                    int n = ct * 16 + cl;
                    bf16x8 bf = *reinterpret_cast<const bf16x8*>(
                        &Bs[(size_t)(n * 16 + (ks ^ (n & 15))) * 8]);
                    acc[ct] = __builtin_amdgcn_mfma_f32_16x16x32_bf16(af, bf, acc[ct], 0, 0, 0);
                }
            }
        }
    }
    __syncthreads();   // ALL waves done reading Bs; LDS becomes per-wave scratch
    if (!act) return;

    // ---- fused epilogue (per wave: 16 rows x 256 cols, C-layout) ----
#pragma unroll
    for (int ct = 0; ct < 16; ++ct) {
        float bc = br[ct * 16 + cl];
#pragma unroll
        for (int r = 0; r < 4; ++r) acc[ct][r] += bc;
    }
    // per-head dots -> logits z[h][r]
    float z[4][4];
#pragma unroll
    for (int h = 0; h < 4; ++h) {
        float sl[4] = {0, 0, 0, 0}, sr[4] = {0, 0, 0, 0};
#pragma unroll
        for (int j = 0; j < 4; ++j) {
            int ct = h * 4 + j;
            float rlc = rl[ct * 16 + cl], rrc = rr[ct * 16 + cl];
#pragma unroll
            for (int r = 0; r < 4; ++r) {
                sl[r] += acc[ct][r] * rlc;
                sr[r] += acc[ct][r] * rrc;
            }
        }
#pragma unroll
        for (int off = 1; off < 16; off <<= 1)
#pragma unroll
            for (int r = 0; r < 4; ++r) {
                sl[r] += __shfl_xor(sl[r], off, 64);
                sr[r] += __shfl_xor(sr[r], off, 64);
            }
#pragma unroll
        for (int r = 0; r < 4; ++r) {
            float x = sl[r] + sr[r];
            z[h][r] = x > 0.f ? x : NEG * x;
        }
    }
    // softmax over heads + count gate (vectorized flag reads)
    uchar4 fq0 = *reinterpret_cast<const uchar4*>(fl + row0 + quad * 4);
    uchar4 fq1 = *reinterpret_cast<const uchar4*>(fl + NN + row0 + quad * 4);
    uchar4 fq2 = *reinterpret_cast<const uchar4*>(fl + 2 * NN + row0 + quad * 4);
    float c0[4] = {(float)fq0.x, (float)fq0.y, (float)fq0.z, (float)fq0.w};
    float c1[4] = {(float)fq1.x, (float)fq1.y, (float)fq1.z, (float)fq1.w};
    float c2[4] = {(float)fq2.x, (float)fq2.y, (float)fq2.z, (float)fq2.w};
    float gg[4][4];   // [h][r]
#pragma unroll
    for (int r = 0; r < 4; ++r) {
        float mx = fmaxf(fmaxf(z[0][r], z[1][r]), fmaxf(z[2][r], z[3][r]));
        float e0 = __expf(z[0][r] - mx), e1 = __expf(z[1][r] - mx);
        float e2 = __expf(z[2][r] - mx), e3 = __expf(z[3][r] - mx);
        float cnt = 1.f + c0[r] + c1[r] + c2[r];
        float inv = cnt / (e0 + e1 + e2 + e3);
        gg[0][r] = e0 * inv; gg[1][r] = e1 * inv;
        gg[2][r] = e2 * inv; gg[3][r] = e3 * inv;
    }
    // gate + LN stats (acc keeps the GATED value; LN applied during store passes)
    float s[4] = {0, 0, 0, 0}, s2[4] = {0, 0, 0, 0};
#pragma unroll
    for (int ct = 0; ct < 16; ++ct) {
        int h = ct >> 2;
#pragma unroll
        for (int r = 0; r < 4; ++r) {
            float o = acc[ct][r] * gg[h][r];
            acc[ct][r] = o;
            s[r] += o;
            s2[r] += o * o;
        }
    }
#pragma unroll
    for (int off = 1; off < 16; off <<= 1)
#pragma unroll
        for (int r = 0; r < 4; ++r) {
            s[r] += __shfl_xor(s[r], off, 64);
            s2[r] += __shfl_xor(s2[r], off, 64);
        }
    float mu[4], rstd[4];
#pragma unroll
    for (int r = 0; r < 4; ++r) {
        mu[r] = s[r] * (1.f / 256.f);
        float var = s2[r] * (1.f / 256.f) - mu[r] * mu[r];
        rstd[r] = rsqrtf(var + EPSV);
    }
    // coalesced store: LN+ReLU folded into per-wave 8KB LDS transpose, 2 passes x 8 rows
    float* tb = reinterpret_cast<float*>(smem) + wave * 2048;
#pragma unroll
    for (int p = 0; p < 2; ++p) {
#pragma unroll
        for (int ct = 0; ct < 16; ++ct) {
            float ga = gamma[ct * 16 + cl], be = beta[ct * 16 + cl];
            float v0 = fmaxf((acc[ct][2 * p + 0] - mu[2 * p + 0]) * rstd[2 * p + 0] * ga + be, 0.f);
            float v1 = fmaxf((acc[ct][2 * p + 1] - mu[2 * p + 1]) * rstd[2 * p + 1] * ga + be, 0.f);
            tb[(quad * 2 + 0) * 256 + ct * 16 + cl] = v0;
            tb[(quad * 2 + 1) * 256 + ct * 16 + cl] = v1;
        }
        LDS_FENCE();   // same-wave cross-lane RAW on LDS
#pragma unroll
        for (int sl8 = 0; sl8 < 8; ++sl8) {
            int trow = (sl8 >> 1) * 4 + 2 * p + (sl8 & 1);
            float4 v4 = *reinterpret_cast<const float4*>(&tb[sl8 * 256 + lane * 4]);
            *reinterpret_cast<float4*>(&out[(size_t)(row0 + trow) * 256 + lane * 4]) = v4;
        }
        LDS_FENCE();   // WAR: reads complete before next pass overwrites
    }
}

extern "C" void kernel_launch(void* const* d_in, const int* in_sizes, int n_in,
                              void* d_out, int out_size, void* d_ws, size_t ws_size,
                              hipStream_t stream) {
    const float* feat = (const float*)d_in[0];
    const float* Wr   = (const float*)d_in[3];
    const float* br   = (const float*)d_in[4];
    const float* rl   = (const float*)d_in[7];
    const float* rr   = (const float*)d_in[8];
    const float* gam  = (const float*)d_in[9];
    const float* bet  = (const float*)d_in[10];
    const int* dst0   = (const int*)d_in[12];
    const int* dst1   = (const int*)d_in[14];
    const int* dst2   = (const int*)d_in[16];
    float* out = (float*)d_out;
    unsigned char* fl  = (unsigned char*)d_ws;                    // 150000 B
    unsigned short* Wt = (unsigned short*)((char*)d_ws + 262144); // 128 KB, 16B-aligned

    hipMemsetAsync(fl, 0, 3 * NN, stream);
    prep_kernel<<<FLB + 8, 256, 0, stream>>>(dst0, dst1, dst2, fl, Wr, Wt);
    fused_kernel<<<512, 512, 0, stream>>>(feat, Wt, br, rl, rr, gam, bet, fl, out);
}